// Round 1
// baseline (99.286 us; speedup 1.0000x reference)
//
#include <hip/hip_runtime.h>
#include <math.h>

#define MODES 32
#define LPT 4            // l-values per thread
#define BLOCK 256
#define CHUNK (BLOCK * LPT)   // 1024 l per block

__global__ __launch_bounds__(BLOCK) void s4d_kernel(
    const float* __restrict__ log_dt,      // (H,)
    const float* __restrict__ C_real,      // (1,H,MODES,2)
    const float* __restrict__ log_A_real,  // (H,MODES)
    const float* __restrict__ A_imag,      // (H,MODES)
    float* __restrict__ out,               // (1,H,L)
    int L, int chunks_per_h)
{
    const int h     = blockIdx.x / chunks_per_h;
    const int chunk = blockIdx.x % chunks_per_h;
    const int tid   = threadIdx.x;

    __shared__ float s_dAr[MODES], s_dAi[MODES];
    __shared__ float s_dCr[MODES], s_dCi[MODES];
    __shared__ float s_xr[MODES],  s_rev[MODES];

    if (tid < MODES) {
        const int n = tid;
        const float dt = __expf(log_dt[h]);
        const float ar = -__expf(log_A_real[h * MODES + n]);
        const float ai = A_imag[h * MODES + n];
        const float dtAr = ar * dt, dtAi = ai * dt;
        // den = 1 - dtA/2 ; num = 1 + dtA/2
        const float den_r = 1.0f - 0.5f * dtAr, den_i = -0.5f * dtAi;
        const float num_r = 1.0f + 0.5f * dtAr, num_i =  0.5f * dtAi;
        const float inv = 1.0f / (den_r * den_r + den_i * den_i);
        // B = dt / den = dt * conj(den) * inv
        const float Br =  dt * den_r * inv;
        const float Bi = -dt * den_i * inv;
        const float Cr = C_real[(h * MODES + n) * 2 + 0];
        const float Ci = C_real[(h * MODES + n) * 2 + 1];
        s_dCr[n] = Cr * Br - Ci * Bi;
        s_dCi[n] = Cr * Bi + Ci * Br;
        // dA = num / den
        const float dAr = (num_r * den_r + num_i * den_i) * inv;
        const float dAi = (num_i * den_r - num_r * den_i) * inv;
        s_dAr[n] = dAr;
        s_dAi[n] = dAi;
        // x = log(dA): real part and imag part in revolutions (for precise phase)
        s_xr[n]  = 0.5f * __logf(dAr * dAr + dAi * dAi);
        s_rev[n] = atan2f(dAi, dAr) * 0.15915494309189535f; // / (2*pi)
    }
    __syncthreads();

    const int l0 = chunk * CHUNK + tid * LPT;
    if (l0 >= L) return;
    const float lf = (float)l0;

    float a0 = 0.f, a1 = 0.f, a2 = 0.f, a3 = 0.f;

    #pragma unroll
    for (int n = 0; n < MODES; ++n) {
        const float xr  = s_xr[n];
        const float rev = s_rev[n];
        const float dAr = s_dAr[n], dAi = s_dAi[n];
        const float dCr = s_dCr[n], dCi = s_dCi[n];

        // p = dA^l0 = exp(xr*l0) * (cos(2pi*frac(rev*l0)) + i sin(...))
        const float er = __expf(xr * lf);
        const float t  = rev * lf;
        const float fr = t - rintf(t);
        const float ang = fr * 6.283185307179586f;
        const float s = __sinf(ang);
        const float c = __cosf(ang);
        float pr = er * c, pi = er * s;

        // l0
        a0 = fmaf(dCr, pr, fmaf(-dCi, pi, a0));
        // l0+1
        float qr = pr * dAr - pi * dAi;
        float qi = pr * dAi + pi * dAr;
        a1 = fmaf(dCr, qr, fmaf(-dCi, qi, a1));
        // l0+2
        pr = qr * dAr - qi * dAi;
        pi = qr * dAi + qi * dAr;
        a2 = fmaf(dCr, pr, fmaf(-dCi, pi, a2));
        // l0+3
        qr = pr * dAr - pi * dAi;
        qi = pr * dAi + pi * dAr;
        a3 = fmaf(dCr, qr, fmaf(-dCi, qi, a3));
    }

    const size_t base = (size_t)h * (size_t)L + (size_t)l0;
    if (l0 + LPT <= L) {
        float4 o = make_float4(2.f * a0, 2.f * a1, 2.f * a2, 2.f * a3);
        *reinterpret_cast<float4*>(&out[base]) = o;
    } else {
        float vals[LPT] = {2.f * a0, 2.f * a1, 2.f * a2, 2.f * a3};
        for (int k = 0; k < LPT && l0 + k < L; ++k) out[base + k] = vals[k];
    }
}

extern "C" void kernel_launch(void* const* d_in, const int* in_sizes, int n_in,
                              void* d_out, int out_size, void* d_ws, size_t ws_size,
                              hipStream_t stream) {
    const float* log_dt     = (const float*)d_in[0];
    const float* C_real     = (const float*)d_in[1];
    const float* log_A_real = (const float*)d_in[2];
    const float* A_imag     = (const float*)d_in[3];
    // d_in[4] is L on device; derive L on host from output size instead.
    float* out = (float*)d_out;

    const int H = in_sizes[0];              // 1024
    const int L = out_size / H;             // 4096
    const int chunks_per_h = (L + CHUNK - 1) / CHUNK;
    const int grid = H * chunks_per_h;

    s4d_kernel<<<grid, BLOCK, 0, stream>>>(log_dt, C_real, log_A_real, A_imag,
                                           out, L, chunks_per_h);
}

// Round 2
// 78.621 us; speedup vs baseline: 1.2629x; 1.2629x over previous
//
#include <hip/hip_runtime.h>
#include <math.h>

#define MODES 32
#define BLOCK 256
#define TWO_PI 6.283185307179586f
#define INV_2PI 0.15915494309189535f

__device__ __forceinline__ float rfl(float x) {
    return __int_as_float(__builtin_amdgcn_readfirstlane(__float_as_int(x)));
}

__global__ __launch_bounds__(BLOCK) void s4d_kernel(
    const float* __restrict__ log_dt,      // (H,)
    const float* __restrict__ C_real,      // (1,H,MODES,2)
    const float* __restrict__ log_A_real,  // (H,MODES)
    const float* __restrict__ A_imag,      // (H,MODES)
    float* __restrict__ out,               // (1,H,L)
    int L)
{
    const int h   = blockIdx.x;
    const int tid = threadIdx.x;
    const int P   = L / BLOCK;             // passes per thread (16 for L=4096)

    __shared__ float4 s_c0[MODES];  // {xr, rev, 2*dCr, 2*dCi}
    __shared__ float4 s_c1[MODES];  // {wr, wi, a, b}   w = dA^BLOCK

    if (tid < MODES) {
        const int n = tid;
        const float dt = __expf(log_dt[h]);
        const float ar = -__expf(log_A_real[h * MODES + n]);
        const float ai = A_imag[h * MODES + n];
        const float dtAr = ar * dt, dtAi = ai * dt;
        const float den_r = 1.0f - 0.5f * dtAr, den_i = -0.5f * dtAi;
        const float num_r = 1.0f + 0.5f * dtAr, num_i =  0.5f * dtAi;
        const float inv = 1.0f / (den_r * den_r + den_i * den_i);
        const float Br =  dt * den_r * inv;
        const float Bi = -dt * den_i * inv;
        const float Cr = C_real[(h * MODES + n) * 2 + 0];
        const float Ci = C_real[(h * MODES + n) * 2 + 1];
        const float dCr = Cr * Br - Ci * Bi;
        const float dCi = Cr * Bi + Ci * Br;
        const float dAr = (num_r * den_r + num_i * den_i) * inv;
        const float dAi = (num_i * den_r - num_r * den_i) * inv;
        const float xr  = 0.5f * __logf(dAr * dAr + dAi * dAi);
        const float rev = atan2f(dAi, dAr) * INV_2PI;   // phase in revolutions

        // w = dA^BLOCK
        const float S   = (float)BLOCK;
        const float mag = __expf(xr * S);
        const float t   = rev * S;
        const float fr  = t - rintf(t);
        float ws, wc;
        __sincosf(fr * TWO_PI, &ws, &wc);
        const float wr = mag * wc, wi = mag * ws;

        s_c0[n] = make_float4(xr, rev, 2.0f * dCr, 2.0f * dCi);
        s_c1[n] = make_float4(wr, wi, 2.0f * wr, -(mag * mag));
    }
    __syncthreads();

    float m0[MODES], m1[MODES];
    float aS[MODES], bS[MODES];
    float acc0 = 0.0f, acc1 = 0.0f;
    const float lf = (float)tid;

    #pragma unroll
    for (int n = 0; n < MODES; ++n) {
        const float4 c0 = s_c0[n];
        const float4 c1 = s_c1[n];
        // p = dA^tid
        const float er = __expf(c0.x * lf);
        const float t  = c0.y * lf;
        const float fr = t - rintf(t);
        float sn, cs;
        __sincosf(fr * TWO_PI, &sn, &cs);
        const float pr = er * cs, pi = er * sn;
        const float v0 = fmaf(c0.z, pr, -c0.w * pi);      // m at l=tid
        // q = p * w  -> dA^(tid+BLOCK)
        const float qr = fmaf(pr, c1.x, -pi * c1.y);
        const float qi = fmaf(pr, c1.y,  pi * c1.x);
        const float v1 = fmaf(c0.z, qr, -c0.w * qi);      // m at l=tid+BLOCK
        m0[n] = v0; m1[n] = v1;
        acc0 += v0; acc1 += v1;
        aS[n] = rfl(c1.z);   // block-uniform -> SGPR
        bS[n] = rfl(c1.w);
    }

    float* outp = out + (size_t)h * (size_t)L + tid;
    outp[0] = acc0;
    if (P > 1) outp[BLOCK] = acc1;

    int p = 2;
    for (; p + 1 < P; p += 2) {
        float accA = 0.0f, accB = 0.0f;
        #pragma unroll
        for (int n = 0; n < MODES; ++n) {
            const float mA = fmaf(aS[n], m1[n], bS[n] * m0[n]);
            const float mB = fmaf(aS[n], mA,    bS[n] * m1[n]);
            accA += mA; accB += mB;
            m0[n] = mA; m1[n] = mB;
        }
        outp[(size_t)p * BLOCK]       = accA;
        outp[(size_t)(p + 1) * BLOCK] = accB;
    }
    if (p < P) {  // odd tail
        float accA = 0.0f;
        #pragma unroll
        for (int n = 0; n < MODES; ++n) {
            const float mA = fmaf(aS[n], m1[n], bS[n] * m0[n]);
            accA += mA;
            m0[n] = m1[n]; m1[n] = mA;
        }
        outp[(size_t)p * BLOCK] = accA;
    }
}

extern "C" void kernel_launch(void* const* d_in, const int* in_sizes, int n_in,
                              void* d_out, int out_size, void* d_ws, size_t ws_size,
                              hipStream_t stream) {
    const float* log_dt     = (const float*)d_in[0];
    const float* C_real     = (const float*)d_in[1];
    const float* log_A_real = (const float*)d_in[2];
    const float* A_imag     = (const float*)d_in[3];
    float* out = (float*)d_out;

    const int H = in_sizes[0];       // 1024
    const int L = out_size / H;      // 4096

    s4d_kernel<<<H, BLOCK, 0, stream>>>(log_dt, C_real, log_A_real, A_imag, out, L);
}

// Round 3
// 71.183 us; speedup vs baseline: 1.3948x; 1.1045x over previous
//
#include <hip/hip_runtime.h>
#include <math.h>

#define MODES 32
#define BLOCK 256
#define TWO_PI 6.283185307179586f
#define INV_2PI 0.15915494309189535f
#define LROWW 36   // padded row stride in 4B words (72 bf16, 144B: 16B-aligned, ~2-way banks)

typedef __attribute__((ext_vector_type(8))) short bf16x8;
typedef __attribute__((ext_vector_type(4))) float f32x4;

// Split x into bf16 hi + bf16 lo (round-to-nearest). Returns packed bits.
__device__ __forceinline__ void split2(float a, float b, unsigned int& hi, unsigned int& lo) {
    unsigned int ua = __float_as_uint(a);
    unsigned int ra = ua + 0x7FFFu + ((ua >> 16) & 1u);
    unsigned int ub = __float_as_uint(b);
    unsigned int rb = ub + 0x7FFFu + ((ub >> 16) & 1u);
    float ha = __uint_as_float(ra & 0xFFFF0000u);
    float hb = __uint_as_float(rb & 0xFFFF0000u);
    float la = a - ha, lb = b - hb;
    unsigned int ula = __float_as_uint(la); ula += 0x7FFFu + ((ula >> 16) & 1u);
    unsigned int ulb = __float_as_uint(lb); ulb += 0x7FFFu + ((ulb >> 16) & 1u);
    hi = (ra >> 16) | (rb & 0xFFFF0000u);
    lo = (ula >> 16) | (ulb & 0xFFFF0000u);
}

// ---------------- MFMA path (L == 4096 = 64 x 64) ----------------
// K[h, 64*i + j] = sum_k A[i,k] * B[k,j],  k = 2*mode (+1)
// A[i,2n]=2*Re(dC_n*W_n^i), A[i,2n+1]=-2*Im(dC_n*W_n^i),  W = dA^64
// B[2n,j]=Re(dA_n^j),       B[2n+1,j]=Im(dA_n^j)
__global__ __launch_bounds__(BLOCK) void s4d_mfma(
    const float* __restrict__ log_dt,
    const float* __restrict__ C_real,
    const float* __restrict__ log_A_real,
    const float* __restrict__ A_imag,
    float* __restrict__ out)
{
    __shared__ __align__(16) unsigned int sAhi[64 * LROWW];
    __shared__ __align__(16) unsigned int sAlo[64 * LROWW];
    __shared__ __align__(16) unsigned int sBhi[64 * LROWW];  // stored as BT[n][k]
    __shared__ __align__(16) unsigned int sBlo[64 * LROWW];
    __shared__ float s_xr[MODES], s_rev[MODES], s_xr64[MODES], s_rev64[MODES];
    __shared__ float s_dcr[MODES], s_dci[MODES];

    const int h = blockIdx.x;
    const int t = threadIdx.x;

    if (t < MODES) {
        const int n = t;
        const float dt = __expf(log_dt[h]);
        const float ar = -__expf(log_A_real[h * MODES + n]);
        const float ai = A_imag[h * MODES + n];
        const float dtAr = ar * dt, dtAi = ai * dt;
        const float den_r = 1.0f - 0.5f * dtAr, den_i = -0.5f * dtAi;
        const float num_r = 1.0f + 0.5f * dtAr, num_i =  0.5f * dtAi;
        const float inv = 1.0f / (den_r * den_r + den_i * den_i);
        const float Br =  dt * den_r * inv;
        const float Bi = -dt * den_i * inv;
        const float Cr = C_real[(h * MODES + n) * 2 + 0];
        const float Ci = C_real[(h * MODES + n) * 2 + 1];
        const float dCr = Cr * Br - Ci * Bi;
        const float dCi = Cr * Bi + Ci * Br;
        const float dAr = (num_r * den_r + num_i * den_i) * inv;
        const float dAi = (num_i * den_r - num_r * den_i) * inv;
        const float xr  = 0.5f * __logf(dAr * dAr + dAi * dAi);   // log|dA|
        const float rev = atan2f(dAi, dAr) * INV_2PI;             // arg(dA) in revolutions
        s_xr[n]  = xr;
        s_rev[n] = rev;
        s_xr64[n] = 64.0f * xr;
        float r64 = 64.0f * rev; r64 -= rintf(r64);
        s_rev64[n] = r64;
        s_dcr[n] = 2.0f * dCr;
        s_dci[n] = 2.0f * dCi;
    }
    __syncthreads();

    // -------- operand generation: thread t owns mode = t&31, idx = (t>>5) + 8b --------
    {
        const int mode = t & 31;
        const int i8   = t >> 5;
        const float xr = s_xr[mode], rev = s_rev[mode];
        const float xr64 = s_xr64[mode], rev64 = s_rev64[mode];
        const float dcr = s_dcr[mode], dci = s_dci[mode];
        #pragma unroll
        for (int b = 0; b < 8; ++b) {
            const int idx = i8 + b * 8;       // both j (for B) and i (for A)
            const float f = (float)idx;
            const int word = idx * LROWW + mode;
            // B: dA^j
            {
                const float er = __expf(xr * f);
                float ph = rev * f; ph -= rintf(ph);
                float sn, cs; __sincosf(ph * TWO_PI, &sn, &cs);
                unsigned int hi, lo;
                split2(er * cs, er * sn, hi, lo);
                sBhi[word] = hi; sBlo[word] = lo;
            }
            // A: 2*dC*W^i (negate imag)
            {
                const float mag = __expf(xr64 * f);
                float ph = rev64 * f; ph -= rintf(ph);
                float sn, cs; __sincosf(ph * TWO_PI, &sn, &cs);
                const float wr = mag * cs, wi = mag * sn;
                const float pr  = dcr * wr - dci * wi;
                const float pi2 = dcr * wi + dci * wr;
                unsigned int hi, lo;
                split2(pr, -pi2, hi, lo);
                sAhi[word] = hi; sAlo[word] = lo;
            }
        }
    }
    __syncthreads();

    // -------- MFMA: wave w computes rows [16w, 16w+16) of the 64x64 C --------
    const int wv   = t >> 6;
    const int lane = t & 63;
    const int c16  = lane & 15;
    const int quad = lane >> 4;

    const int arow = (wv * 16 + c16) * LROWW + quad * 4;
    const bf16x8 ah0 = *(const bf16x8*)&sAhi[arow];
    const bf16x8 ah1 = *(const bf16x8*)&sAhi[arow + 16];
    const bf16x8 al0 = *(const bf16x8*)&sAlo[arow];
    const bf16x8 al1 = *(const bf16x8*)&sAlo[arow + 16];

    float* op = out + ((size_t)h << 12) + (size_t)(wv * 16 + quad * 4) * 64 + c16;

    #pragma unroll
    for (int nt = 0; nt < 4; ++nt) {
        const int brow = (nt * 16 + c16) * LROWW + quad * 4;
        const bf16x8 bh0 = *(const bf16x8*)&sBhi[brow];
        const bf16x8 bh1 = *(const bf16x8*)&sBhi[brow + 16];
        const bf16x8 bl0 = *(const bf16x8*)&sBlo[brow];
        const bf16x8 bl1 = *(const bf16x8*)&sBlo[brow + 16];

        f32x4 acc = {0.f, 0.f, 0.f, 0.f};
        acc = __builtin_amdgcn_mfma_f32_16x16x32_bf16(ah0, bh0, acc, 0, 0, 0);
        acc = __builtin_amdgcn_mfma_f32_16x16x32_bf16(ah1, bh1, acc, 0, 0, 0);
        acc = __builtin_amdgcn_mfma_f32_16x16x32_bf16(ah0, bl0, acc, 0, 0, 0);
        acc = __builtin_amdgcn_mfma_f32_16x16x32_bf16(ah1, bl1, acc, 0, 0, 0);
        acc = __builtin_amdgcn_mfma_f32_16x16x32_bf16(al0, bh0, acc, 0, 0, 0);
        acc = __builtin_amdgcn_mfma_f32_16x16x32_bf16(al1, bh1, acc, 0, 0, 0);

        #pragma unroll
        for (int r = 0; r < 4; ++r)
            op[(size_t)r * 64 + nt * 16] = acc[r];
    }
}

// ---------------- fallback: stride-256 real recurrence (any L % 256 == 0) ----------------
__global__ __launch_bounds__(BLOCK) void s4d_recur(
    const float* __restrict__ log_dt, const float* __restrict__ C_real,
    const float* __restrict__ log_A_real, const float* __restrict__ A_imag,
    float* __restrict__ out, int L)
{
    const int h = blockIdx.x, tid = threadIdx.x;
    const int P = L / BLOCK;
    __shared__ float4 s_c0[MODES], s_c1[MODES];
    if (tid < MODES) {
        const int n = tid;
        const float dt = __expf(log_dt[h]);
        const float ar = -__expf(log_A_real[h * MODES + n]);
        const float ai = A_imag[h * MODES + n];
        const float dtAr = ar * dt, dtAi = ai * dt;
        const float den_r = 1.0f - 0.5f * dtAr, den_i = -0.5f * dtAi;
        const float num_r = 1.0f + 0.5f * dtAr, num_i = 0.5f * dtAi;
        const float inv = 1.0f / (den_r * den_r + den_i * den_i);
        const float Brr = dt * den_r * inv, Bii = -dt * den_i * inv;
        const float Cr = C_real[(h * MODES + n) * 2 + 0];
        const float Ci = C_real[(h * MODES + n) * 2 + 1];
        const float dCr = Cr * Brr - Ci * Bii, dCi = Cr * Bii + Ci * Brr;
        const float dAr = (num_r * den_r + num_i * den_i) * inv;
        const float dAi = (num_i * den_r - num_r * den_i) * inv;
        const float xr = 0.5f * __logf(dAr * dAr + dAi * dAi);
        const float rev = atan2f(dAi, dAr) * INV_2PI;
        const float S = (float)BLOCK;
        const float mag = __expf(xr * S);
        float tt = rev * S; tt -= rintf(tt);
        float ws, wc; __sincosf(tt * TWO_PI, &ws, &wc);
        s_c0[n] = make_float4(xr, rev, 2.0f * dCr, 2.0f * dCi);
        s_c1[n] = make_float4(mag * wc, mag * ws, 2.0f * mag * wc, -(mag * mag));
    }
    __syncthreads();
    float m0[MODES], m1[MODES], aS[MODES], bS[MODES];
    float acc0 = 0.f, acc1 = 0.f;
    const float lf = (float)tid;
    #pragma unroll
    for (int n = 0; n < MODES; ++n) {
        const float4 c0 = s_c0[n]; const float4 c1 = s_c1[n];
        const float er = __expf(c0.x * lf);
        float tt = c0.y * lf; tt -= rintf(tt);
        float sn, cs; __sincosf(tt * TWO_PI, &sn, &cs);
        const float pr = er * cs, pi = er * sn;
        const float v0 = fmaf(c0.z, pr, -c0.w * pi);
        const float qr = fmaf(pr, c1.x, -pi * c1.y);
        const float qi = fmaf(pr, c1.y, pi * c1.x);
        const float v1 = fmaf(c0.z, qr, -c0.w * qi);
        m0[n] = v0; m1[n] = v1; acc0 += v0; acc1 += v1;
        aS[n] = c1.z; bS[n] = c1.w;
    }
    float* outp = out + (size_t)h * (size_t)L + tid;
    outp[0] = acc0;
    if (P > 1) outp[BLOCK] = acc1;
    int p = 2;
    for (; p + 1 < P; p += 2) {
        float accA = 0.f, accB = 0.f;
        #pragma unroll
        for (int n = 0; n < MODES; ++n) {
            const float mA = fmaf(aS[n], m1[n], bS[n] * m0[n]);
            const float mB = fmaf(aS[n], mA, bS[n] * m1[n]);
            accA += mA; accB += mB; m0[n] = mA; m1[n] = mB;
        }
        outp[(size_t)p * BLOCK] = accA;
        outp[(size_t)(p + 1) * BLOCK] = accB;
    }
    if (p < P) {
        float accA = 0.f;
        #pragma unroll
        for (int n = 0; n < MODES; ++n) {
            const float mA = fmaf(aS[n], m1[n], bS[n] * m0[n]);
            accA += mA; m0[n] = m1[n]; m1[n] = mA;
        }
        outp[(size_t)p * BLOCK] = accA;
    }
}

extern "C" void kernel_launch(void* const* d_in, const int* in_sizes, int n_in,
                              void* d_out, int out_size, void* d_ws, size_t ws_size,
                              hipStream_t stream) {
    const float* log_dt     = (const float*)d_in[0];
    const float* C_real     = (const float*)d_in[1];
    const float* log_A_real = (const float*)d_in[2];
    const float* A_imag     = (const float*)d_in[3];
    float* out = (float*)d_out;

    const int H = in_sizes[0];
    const int L = out_size / H;

    if (L == 4096) {
        s4d_mfma<<<H, BLOCK, 0, stream>>>(log_dt, C_real, log_A_real, A_imag, out);
    } else {
        s4d_recur<<<H, BLOCK, 0, stream>>>(log_dt, C_real, log_A_real, A_imag, out, L);
    }
}

// Round 4
// 69.883 us; speedup vs baseline: 1.4207x; 1.0186x over previous
//
#include <hip/hip_runtime.h>
#include <hip/hip_bf16.h>
#include <math.h>

#define MODES 32
#define BLOCK 256
#define TWO_PI 6.283185307179586f
#define INV_2PI 0.15915494309189535f
#define LROWW 36   // padded row stride in 4B words (72 bf16, 144B: 16B-aligned)

typedef __attribute__((ext_vector_type(8))) short bf16x8;
typedef __attribute__((ext_vector_type(4))) float f32x4;

__device__ __forceinline__ unsigned int pk_bf16(float a, float b) {
    __hip_bfloat162 h = __float22bfloat162_rn(float2{a, b});
    union { __hip_bfloat162 v; unsigned int u; } cv; cv.v = h;
    return cv.u;
}

// hi = bf16(a)|bf16(b) packed; lo = bf16 of residuals
__device__ __forceinline__ void split2(float a, float b, unsigned int& hi, unsigned int& lo) {
    hi = pk_bf16(a, b);
    const float ha = __uint_as_float((hi & 0xFFFFu) << 16);
    const float hb = __uint_as_float(hi & 0xFFFF0000u);
    lo = pk_bf16(a - ha, b - hb);
}

// ---------------- MFMA path (L == 4096 = 64 x 64) ----------------
// K[h, 64*i + j] = sum_k A[i,k] * B[k,j],  k = 2*mode (+1)
// A[i,2n]=2*Re(dC_n*W_n^i), A[i,2n+1]=-2*Im(dC_n*W_n^i),  W = dA^64
// B[2n,j]=Re(dA_n^j),       B[2n+1,j]=Im(dA_n^j)
__global__ __launch_bounds__(BLOCK) void s4d_mfma(
    const float* __restrict__ log_dt,
    const float* __restrict__ C_real,
    const float* __restrict__ log_A_real,
    const float* __restrict__ A_imag,
    float* __restrict__ out)
{
    __shared__ __align__(16) unsigned int sAhi[64 * LROWW];
    __shared__ __align__(16) unsigned int sAlo[64 * LROWW];
    __shared__ __align__(16) unsigned int sBhi[64 * LROWW];  // BT[j][k]
    __shared__ __align__(16) unsigned int sBlo[64 * LROWW];

    const int h = blockIdx.x;
    const int t = threadIdx.x;
    const int mode = t & 31;
    const int i8   = t >> 5;       // 0..7

    // ---- per-thread discretization (redundant across i8 groups, cheap) ----
    const float dt = __expf(log_dt[h]);
    const float ar = -__expf(log_A_real[h * MODES + mode]);
    const float ai = A_imag[h * MODES + mode];
    const float dtAr = ar * dt, dtAi = ai * dt;
    const float den_r = 1.0f - 0.5f * dtAr, den_i = -0.5f * dtAi;
    const float num_r = 1.0f + 0.5f * dtAr, num_i =  0.5f * dtAi;
    const float inv = 1.0f / (den_r * den_r + den_i * den_i);
    const float Br =  dt * den_r * inv;
    const float Bi = -dt * den_i * inv;
    const float Cr = C_real[(h * MODES + mode) * 2 + 0];
    const float Ci = C_real[(h * MODES + mode) * 2 + 1];
    const float dcr2 = 2.0f * (Cr * Br - Ci * Bi);
    const float dci2 = 2.0f * (Cr * Bi + Ci * Br);
    const float dAr = (num_r * den_r + num_i * den_i) * inv;
    const float dAi = (num_i * den_r - num_r * den_i) * inv;
    const float xr  = 0.5f * __logf(dAr * dAr + dAi * dAi);   // log|dA|
    const float rev = atan2f(dAi, dAr) * INV_2PI;             // arg in revolutions

    // W = dA^64
    const float mag64 = __expf(64.0f * xr);
    float r64 = 64.0f * rev; r64 -= rintf(r64);
    float w_s, w_c; __sincosf(r64 * TWO_PI, &w_s, &w_c);
    const float Wr = mag64 * w_c, Wi = mag64 * w_s;

    // ---- seeds at s = 8*i8 ----
    const float s = (float)(i8 * 8);
    // B seed: dA^s
    float er = __expf(xr * s);
    float ph = rev * s; ph -= rintf(ph);
    float sn, cs; __sincosf(ph * TWO_PI, &sn, &cs);
    float br = er * cs, bi = er * sn;
    // A seed: dC2 * W^s
    float mags = __expf(64.0f * xr * s);
    float ph2 = r64 * s; ph2 -= rintf(ph2);
    float sn2, cs2; __sincosf(ph2 * TWO_PI, &sn2, &cs2);
    const float wsr = mags * cs2, wsi = mags * sn2;
    float pr = dcr2 * wsr - dci2 * wsi;
    float pi = dcr2 * wsi + dci2 * wsr;

    int base = (i8 * 8) * LROWW + mode;
    #pragma unroll
    for (int b = 0; b < 8; ++b) {
        unsigned int hi, lo;
        split2(br, bi, hi, lo);
        sBhi[base] = hi; sBlo[base] = lo;
        split2(pr, -pi, hi, lo);
        sAhi[base] = hi; sAlo[base] = lo;
        // step B by dA, A by W
        const float nbr = fmaf(br, dAr, -(bi * dAi));
        const float nbi = fmaf(br, dAi,   bi * dAr);
        br = nbr; bi = nbi;
        const float npr = fmaf(pr, Wr, -(pi * Wi));
        const float npi = fmaf(pr, Wi,   pi * Wr);
        pr = npr; pi = npi;
        base += LROWW;
    }
    __syncthreads();

    // -------- MFMA: wave w computes rows [16w, 16w+16) of the 64x64 C --------
    const int wv   = t >> 6;
    const int lane = t & 63;
    const int c16  = lane & 15;
    const int quad = lane >> 4;

    const int arow = (wv * 16 + c16) * LROWW + quad * 4;
    const bf16x8 ah0 = *(const bf16x8*)&sAhi[arow];
    const bf16x8 ah1 = *(const bf16x8*)&sAhi[arow + 16];
    const bf16x8 al0 = *(const bf16x8*)&sAlo[arow];
    const bf16x8 al1 = *(const bf16x8*)&sAlo[arow + 16];

    float* op = out + ((size_t)h << 12) + (size_t)(wv * 16 + quad * 4) * 64 + c16;

    #pragma unroll
    for (int nt = 0; nt < 4; ++nt) {
        const int brow = (nt * 16 + c16) * LROWW + quad * 4;
        const bf16x8 bh0 = *(const bf16x8*)&sBhi[brow];
        const bf16x8 bh1 = *(const bf16x8*)&sBhi[brow + 16];
        const bf16x8 bl0 = *(const bf16x8*)&sBlo[brow];
        const bf16x8 bl1 = *(const bf16x8*)&sBlo[brow + 16];

        f32x4 acc = {0.f, 0.f, 0.f, 0.f};
        acc = __builtin_amdgcn_mfma_f32_16x16x32_bf16(ah0, bh0, acc, 0, 0, 0);
        acc = __builtin_amdgcn_mfma_f32_16x16x32_bf16(ah1, bh1, acc, 0, 0, 0);
        acc = __builtin_amdgcn_mfma_f32_16x16x32_bf16(ah0, bl0, acc, 0, 0, 0);
        acc = __builtin_amdgcn_mfma_f32_16x16x32_bf16(ah1, bl1, acc, 0, 0, 0);
        acc = __builtin_amdgcn_mfma_f32_16x16x32_bf16(al0, bh0, acc, 0, 0, 0);
        acc = __builtin_amdgcn_mfma_f32_16x16x32_bf16(al1, bh1, acc, 0, 0, 0);

        #pragma unroll
        for (int r = 0; r < 4; ++r)
            op[(size_t)r * 64 + nt * 16] = acc[r];
    }
}

// ---------------- fallback: stride-256 real recurrence (any L % 256 == 0) ----------------
__global__ __launch_bounds__(BLOCK) void s4d_recur(
    const float* __restrict__ log_dt, const float* __restrict__ C_real,
    const float* __restrict__ log_A_real, const float* __restrict__ A_imag,
    float* __restrict__ out, int L)
{
    const int h = blockIdx.x, tid = threadIdx.x;
    const int P = L / BLOCK;
    __shared__ float4 s_c0[MODES], s_c1[MODES];
    if (tid < MODES) {
        const int n = tid;
        const float dt = __expf(log_dt[h]);
        const float ar = -__expf(log_A_real[h * MODES + n]);
        const float ai = A_imag[h * MODES + n];
        const float dtAr = ar * dt, dtAi = ai * dt;
        const float den_r = 1.0f - 0.5f * dtAr, den_i = -0.5f * dtAi;
        const float num_r = 1.0f + 0.5f * dtAr, num_i = 0.5f * dtAi;
        const float inv = 1.0f / (den_r * den_r + den_i * den_i);
        const float Brr = dt * den_r * inv, Bii = -dt * den_i * inv;
        const float Cr = C_real[(h * MODES + n) * 2 + 0];
        const float Ci = C_real[(h * MODES + n) * 2 + 1];
        const float dCr = Cr * Brr - Ci * Bii, dCi = Cr * Bii + Ci * Brr;
        const float dAr = (num_r * den_r + num_i * den_i) * inv;
        const float dAi = (num_i * den_r - num_r * den_i) * inv;
        const float xr = 0.5f * __logf(dAr * dAr + dAi * dAi);
        const float rev = atan2f(dAi, dAr) * INV_2PI;
        const float S = (float)BLOCK;
        const float mag = __expf(xr * S);
        float tt = rev * S; tt -= rintf(tt);
        float ws, wc; __sincosf(tt * TWO_PI, &ws, &wc);
        s_c0[n] = make_float4(xr, rev, 2.0f * dCr, 2.0f * dCi);
        s_c1[n] = make_float4(mag * wc, mag * ws, 2.0f * mag * wc, -(mag * mag));
    }
    __syncthreads();
    float m0[MODES], m1[MODES], aS[MODES], bS[MODES];
    float acc0 = 0.f, acc1 = 0.f;
    const float lf = (float)tid;
    #pragma unroll
    for (int n = 0; n < MODES; ++n) {
        const float4 c0 = s_c0[n]; const float4 c1 = s_c1[n];
        const float er = __expf(c0.x * lf);
        float tt = c0.y * lf; tt -= rintf(tt);
        float sn, cs; __sincosf(tt * TWO_PI, &sn, &cs);
        const float pr = er * cs, pi = er * sn;
        const float v0 = fmaf(c0.z, pr, -c0.w * pi);
        const float qr = fmaf(pr, c1.x, -pi * c1.y);
        const float qi = fmaf(pr, c1.y, pi * c1.x);
        const float v1 = fmaf(c0.z, qr, -c0.w * qi);
        m0[n] = v0; m1[n] = v1; acc0 += v0; acc1 += v1;
        aS[n] = c1.z; bS[n] = c1.w;
    }
    float* outp = out + (size_t)h * (size_t)L + tid;
    outp[0] = acc0;
    if (P > 1) outp[BLOCK] = acc1;
    int p = 2;
    for (; p + 1 < P; p += 2) {
        float accA = 0.f, accB = 0.f;
        #pragma unroll
        for (int n = 0; n < MODES; ++n) {
            const float mA = fmaf(aS[n], m1[n], bS[n] * m0[n]);
            const float mB = fmaf(aS[n], mA, bS[n] * m1[n]);
            accA += mA; accB += mB; m0[n] = mA; m1[n] = mB;
        }
        outp[(size_t)p * BLOCK] = accA;
        outp[(size_t)(p + 1) * BLOCK] = accB;
    }
    if (p < P) {
        float accA = 0.f;
        #pragma unroll
        for (int n = 0; n < MODES; ++n) {
            const float mA = fmaf(aS[n], m1[n], bS[n] * m0[n]);
            accA += mA; m0[n] = m1[n]; m1[n] = mA;
        }
        outp[(size_t)p * BLOCK] = accA;
    }
}

extern "C" void kernel_launch(void* const* d_in, const int* in_sizes, int n_in,
                              void* d_out, int out_size, void* d_ws, size_t ws_size,
                              hipStream_t stream) {
    const float* log_dt     = (const float*)d_in[0];
    const float* C_real     = (const float*)d_in[1];
    const float* log_A_real = (const float*)d_in[2];
    const float* A_imag     = (const float*)d_in[3];
    float* out = (float*)d_out;

    const int H = in_sizes[0];
    const int L = out_size / H;

    if (L == 4096) {
        s4d_mfma<<<H, BLOCK, 0, stream>>>(log_dt, C_real, log_A_real, A_imag, out);
    } else {
        s4d_recur<<<H, BLOCK, 0, stream>>>(log_dt, C_real, log_A_real, A_imag, out, L);
    }
}